// Round 5
// baseline (1462.459 us; speedup 1.0000x reference)
//
#include <hip/hip_runtime.h>
#include <hip/hip_bf16.h>
#include <cstddef>

typedef unsigned short u16;
typedef unsigned int   u32;
typedef unsigned long long u64;
typedef short v8s __attribute__((ext_vector_type(8)));
typedef u16   v8u __attribute__((ext_vector_type(8)));
typedef float v4f __attribute__((ext_vector_type(4)));

#define CH  256
#define NSP 4096
#define NB  2

__device__ __forceinline__ float b2f(u16 u){ u32 t = ((u32)u) << 16; float f; __builtin_memcpy(&f, &t, 4); return f; }
__device__ __forceinline__ u16 f2b(float f){
  u32 x; __builtin_memcpy(&x, &f, 4);
  u32 r = x + 0x7FFFu + ((x >> 16) & 1u);
  return (u16)(r >> 16);
}
__device__ __forceinline__ u32 f2sortable(float f){
  u32 x; __builtin_memcpy(&x, &f, 4);
  return (x & 0x80000000u) ? ~x : (x | 0x80000000u);
}
__device__ __forceinline__ float sortable2f(u32 u){
  u32 x = (u & 0x80000000u) ? (u ^ 0x80000000u) : ~u;
  float f; __builtin_memcpy(&f, &x, 4);
  return f;
}

// ---------------- per-(b,c) mean / rstd over fp32 input (fp64 accumulate) ----------------
__global__ __launch_bounds__(256) void k_stats(
    const float* __restrict__ x0, const float* __restrict__ x1,
    const float* __restrict__ x2, const float* __restrict__ x3,
    float* __restrict__ meanv, float* __restrict__ rstdv){
  int bid = blockIdx.x;            // t*512 + row
  int t = bid >> 9, row = bid & 511;
  const float* src = (t==0?x0: t==1?x1: t==2?x2: x3) + (size_t)row*NSP;
  int tid = threadIdx.x;
  double sx = 0.0, sq = 0.0;
  const float4* p4 = (const float4*)src;
  #pragma unroll
  for (int k=0;k<4;k++){
    float4 v = p4[tid + k*256];
    double a=v.x,bb=v.y,c=v.z,d=v.w;
    sx += a+bb+c+d;
    sq += a*a + bb*bb + c*c + d*d;
  }
  #pragma unroll
  for (int off=1; off<64; off<<=1){ sx += __shfl_xor(sx, off); sq += __shfl_xor(sq, off); }
  __shared__ double wsx[4], wsq[4];
  int w = tid >> 6;
  if ((tid & 63) == 0){ wsx[w] = sx; wsq[w] = sq; }
  __syncthreads();
  if (tid == 0){
    double SX = wsx[0]+wsx[1]+wsx[2]+wsx[3];
    double SQ = wsq[0]+wsq[1]+wsq[2]+wsq[3];
    double mean = SX / 4096.0;
    double var  = (SQ - 4096.0*mean*mean) / 4095.0;
    double rstd = 1.0 / sqrt(var + 1e-5);
    meanv[bid] = (float)mean;
    rstdv[bid] = (float)rstd;
  }
}

// ---------------- weight prep: W2 = Wo@Wh (bf16 out), b2 = Wo@bh + bo ----------------
__global__ __launch_bounds__(256) void k_weights(
    const float* __restrict__ Wo, const float* __restrict__ Wh,
    const float* __restrict__ bh, const float* __restrict__ bo,
    u16* __restrict__ W2, float* __restrict__ b2v){
  int o = blockIdx.x, c = threadIdx.x;
  __shared__ float wo[256];
  __shared__ float red[256];
  wo[c] = Wo[o*256 + c];
  __syncthreads();
  float acc = 0.f;
  for (int j=0;j<256;j++) acc += wo[j] * Wh[j*256 + c];
  W2[o*256 + c] = f2b(acc);
  red[c] = wo[c] * bh[c];
  __syncthreads();
  for (int s=128;s>0;s>>=1){ if (c < s) red[c] += red[c+s]; __syncthreads(); }
  if (c == 0) b2v[o] = red[0] + bo[o];
}

// ---------------- mask bitmap: bit=1 where map >= 0.5 (keep) ----------------
__global__ __launch_bounds__(256) void k_maskbits(
    const float* __restrict__ map, u32* __restrict__ bits){
  int wid = blockIdx.x*256 + threadIdx.x;      // [0, 4096*128)
  const float4* p = (const float4*)(map + (size_t)wid*32);
  u32 m = 0;
  #pragma unroll
  for (int k=0;k<8;k++){
    float4 v = p[k];
    m |= (u32)(v.x >= 0.5f) << (k*4+0);
    m |= (u32)(v.y >= 0.5f) << (k*4+1);
    m |= (u32)(v.z >= 0.5f) << (k*4+2);
    m |= (u32)(v.w >= 0.5f) << (k*4+3);
  }
  bits[wid] = m;
}

// ---------- SCA conv (approx): out[b][n][o]=bf16( sum_c W[o][c]*mvn(x)[c][n] + bias[o] ) ----------
__global__ __launch_bounds__(256,2) void k_conv_sca(
    const float* __restrict__ x, const float* __restrict__ W,
    const float* __restrict__ meanv, const float* __restrict__ rstdv, int statBase,
    const float* __restrict__ biasv, u16* __restrict__ outB){
  __shared__ u16 As[64][72];
  __shared__ u16 Bs[64][72];
  int o0 = blockIdx.x*64, n0 = blockIdx.y*64, b = blockIdx.z;
  int tid = threadIdx.x, w = tid>>6, lane = tid&63, col = lane&15, q = lane>>4;
  v4f acc[4] = {};
  int crA = tid>>2, nseg = (tid&3)*16;
  for (int kc=0; kc<4; kc++){
    int cg = kc*64;
    { // A: mvn + bf16 + transpose
      int srow = statBase + b*256 + cg + crA;
      float mean = meanv[srow], rstd = rstdv[srow];
      const float4* xr = (const float4*)(x + ((size_t)(b*256 + cg + crA))*NSP + n0 + nseg);
      #pragma unroll
      for (int k4=0;k4<4;k4++){
        float4 v = xr[k4];
        As[nseg+k4*4+0][crA] = f2b((v.x-mean)*rstd);
        As[nseg+k4*4+1][crA] = f2b((v.y-mean)*rstd);
        As[nseg+k4*4+2][crA] = f2b((v.z-mean)*rstd);
        As[nseg+k4*4+3][crA] = f2b((v.w-mean)*rstd);
      }
    }
    { // B: weights rows
      const float4* wr = (const float4*)(W + ((size_t)(o0 + crA))*256 + cg + nseg);
      #pragma unroll
      for (int h=0;h<2;h++){
        float4 a = wr[h*2], c = wr[h*2+1];
        v8u o;
        o[0]=f2b(a.x); o[1]=f2b(a.y); o[2]=f2b(a.z); o[3]=f2b(a.w);
        o[4]=f2b(c.x); o[5]=f2b(c.y); o[6]=f2b(c.z); o[7]=f2b(c.w);
        *(v8u*)&Bs[crA][nseg + h*8] = o;
      }
    }
    __syncthreads();
    #pragma unroll
    for (int ks=0;ks<2;ks++){
      v8s af = *(v8s*)&As[w*16 + col][ks*32 + q*8];
      #pragma unroll
      for (int js=0;js<4;js++){
        v8s bfr = *(v8s*)&Bs[js*16 + col][ks*32 + q*8];
        acc[js] = __builtin_amdgcn_mfma_f32_16x16x32_bf16(af, bfr, acc[js], 0, 0, 0);
      }
    }
    __syncthreads();
  }
  #pragma unroll
  for (int js=0;js<4;js++){
    int o = o0 + js*16 + col;
    float bj = biasv[o];
    #pragma unroll
    for (int reg=0;reg<4;reg++){
      int n = n0 + w*16 + q*4 + reg;
      outB[((size_t)(b*NSP + n))*256 + o] = f2b(acc[js][reg] + bj);
    }
  }
}

// ---------- SSA conv (fp32-exact): 6-term bf16 split (i+j<=2), fp32 out (+opt bf16) ----------
__global__ __launch_bounds__(256,2) void k_conv_ssa(
    const float* __restrict__ x, const float* __restrict__ W,
    const float* __restrict__ meanv, const float* __restrict__ rstdv, int statBase,
    const float* __restrict__ biasv,
    float* __restrict__ outF, u16* __restrict__ outB){
  __shared__ u32 As32[64][100];
  __shared__ u32 Bs32[64][100];
  int o0 = blockIdx.x*64, n0 = blockIdx.y*64, b = blockIdx.z;
  int tid = threadIdx.x, w = tid>>6, lane = tid&63, col = lane&15, q = lane>>4;
  v4f acc[4] = {};
  int cA = tid>>3, nnA = (tid&7)*8;
  int oB = tid>>2, cB = (tid&3)*8;
  for (int g=0; g<8; g++){
    int cg = g*32;
    { // A: mvn + 3-way split, slots per ch: (x0,x1,x2,x0,x1,x0)
      int srow = statBase + b*256 + cg + cA;
      float mean = meanv[srow], rstd = rstdv[srow];
      const float4* xr = (const float4*)(x + ((size_t)(b*256 + cg + cA))*NSP + n0 + nnA);
      float4 v0 = xr[0], v1 = xr[1];
      float xv[8] = {v0.x,v0.y,v0.z,v0.w,v1.x,v1.y,v1.z,v1.w};
      #pragma unroll
      for (int e=0;e<8;e++){
        float xm = (xv[e]-mean)*rstd;
        u16 s0 = f2b(xm);  float r1 = xm - b2f(s0);
        u16 s1 = f2b(r1);  float r2 = r1 - b2f(s1);
        u16 s2 = f2b(r2);
        As32[nnA+e][cA*3+0] = (u32)s0 | ((u32)s1<<16);
        As32[nnA+e][cA*3+1] = (u32)s2 | ((u32)s0<<16);
        As32[nnA+e][cA*3+2] = (u32)s1 | ((u32)s0<<16);
      }
    }
    { // B: 3-way split of W, slots per ch: (w0,w0,w0,w1,w1,w2)
      const float4* wr = (const float4*)(W + ((size_t)(o0 + oB))*256 + cg + cB);
      float4 w0v = wr[0], w1v = wr[1];
      float wv[8] = {w0v.x,w0v.y,w0v.z,w0v.w,w1v.x,w1v.y,w1v.z,w1v.w};
      #pragma unroll
      for (int e=0;e<8;e++){
        float ww = wv[e];
        u16 t0 = f2b(ww);  float r1 = ww - b2f(t0);
        u16 t1 = f2b(r1);  float r2 = r1 - b2f(t1);
        u16 t2 = f2b(r2);
        int cc = cB + e;
        Bs32[oB][cc*3+0] = (u32)t0 | ((u32)t0<<16);
        Bs32[oB][cc*3+1] = (u32)t0 | ((u32)t1<<16);
        Bs32[oB][cc*3+2] = (u32)t1 | ((u32)t2<<16);
      }
    }
    __syncthreads();
    #pragma unroll
    for (int ks=0;ks<6;ks++){
      v8s af = *(v8s*)&As32[w*16 + col][ks*16 + q*4];
      #pragma unroll
      for (int js=0;js<4;js++){
        v8s bfr = *(v8s*)&Bs32[js*16 + col][ks*16 + q*4];
        acc[js] = __builtin_amdgcn_mfma_f32_16x16x32_bf16(af, bfr, acc[js], 0, 0, 0);
      }
    }
    __syncthreads();
  }
  #pragma unroll
  for (int js=0;js<4;js++){
    int o = o0 + js*16 + col;
    float bj = biasv[o];
    #pragma unroll
    for (int reg=0;reg<4;reg++){
      int n = n0 + w*16 + q*4 + reg;
      float v = acc[js][reg] + bj;
      size_t idx = ((size_t)(b*NSP + n))*256 + o;
      outF[idx] = v;
      if (outB) outB[idx] = f2b(v);
    }
  }
}

// ---------------- V' = W2 @ style + b2 -> vp[b][o][m] (bf16) ----------------
__global__ __launch_bounds__(256,2) void k_vprime(
    const u16* __restrict__ w2, const float* __restrict__ style,
    const float* __restrict__ b2v, u16* __restrict__ vp){
  __shared__ u16 As[64][72];
  __shared__ u16 Bs[64][72];
  int m0 = blockIdx.x*64, o0 = blockIdx.y*64, b = blockIdx.z;
  int tid = threadIdx.x, w = tid>>6, lane = tid&63, col = lane&15, q = lane>>4;
  v4f acc[4] = {};
  for (int kc=0; kc<4; kc++){
    int cg = kc*64;
    #pragma unroll
    for (int p=0;p<2;p++){
      int id = tid + p*256;
      int row = id>>3, cc = (id&7)*8;
      *(v8s*)&As[row][cc] = *(const v8s*)(w2 + ((size_t)(o0+row))*256 + cg + cc);
    }
    {
      int cr = tid>>2, mseg = (tid&3)*16;
      const float4* sr = (const float4*)(style + ((size_t)(b*256 + cg + cr))*NSP + m0 + mseg);
      #pragma unroll
      for (int k4=0;k4<4;k4++){
        float4 v = sr[k4];
        Bs[mseg+k4*4+0][cr] = f2b(v.x);
        Bs[mseg+k4*4+1][cr] = f2b(v.y);
        Bs[mseg+k4*4+2][cr] = f2b(v.z);
        Bs[mseg+k4*4+3][cr] = f2b(v.w);
      }
    }
    __syncthreads();
    #pragma unroll
    for (int ks=0;ks<2;ks++){
      v8s af = *(v8s*)&As[w*16+col][ks*32+q*8];
      #pragma unroll
      for (int js=0;js<4;js++){
        v8s bfr = *(v8s*)&Bs[js*16+col][ks*32+q*8];
        acc[js] = __builtin_amdgcn_mfma_f32_16x16x32_bf16(af, bfr, acc[js], 0,0,0);
      }
    }
    __syncthreads();
  }
  #pragma unroll
  for (int js=0;js<4;js++){
    int m = m0 + js*16 + col;
    #pragma unroll
    for (int reg=0;reg<4;reg++){
      int o = o0 + w*16 + q*4 + reg;
      vp[((size_t)(b*CH + o))*NSP + m] = f2b(acc[js][reg] + b2v[o]);
    }
  }
}

// ---------------- SSA pass A (new): masked bf16 score dump, one batch ----------------
__global__ __launch_bounds__(256,2) void k_ssa_dump(
    const u16* __restrict__ Qt, const u16* __restrict__ Kt,
    const u32* __restrict__ mbits, int b, u16* __restrict__ Sb){
  __shared__ u16 Ks[64][264];
  int mh = blockIdx.x, nt = blockIdx.y;
  int tid = threadIdx.x, w = tid>>6, lane = tid&63, col = lane&15, q = lane>>4;
  int nw = nt*64 + w*16, mbase = mh*512;
  v8s qf[8];
  const u16* qrow = Qt + ((size_t)(b*NSP + nw + col))*256;
  #pragma unroll
  for (int ks=0;ks<8;ks++) qf[ks] = *(const v8s*)(qrow + ks*32 + q*8);
  for (int it=0; it<8; it++){
    int m0 = mbase + it*64;
    #pragma unroll
    for (int p=0;p<8;p++){
      int id = tid + p*256;
      int row = id>>5, cc = (id&31)*8;
      *(v8s*)&Ks[row][cc] = *(const v8s*)(Kt + ((size_t)(b*NSP + m0 + row))*256 + cc);
    }
    __syncthreads();
    v4f as[4] = {};
    #pragma unroll
    for (int ks=0;ks<8;ks++){
      #pragma unroll
      for (int js=0;js<4;js++){
        v8s bfr = *(v8s*)&Ks[js*16+col][ks*32+q*8];
        as[js] = __builtin_amdgcn_mfma_f32_16x16x32_bf16(qf[ks], bfr, as[js], 0, 0, 0);
      }
    }
    #pragma unroll
    for (int reg=0;reg<4;reg++){
      int ng = nw + q*4 + reg;
      u64 mw = *(const u64*)(mbits + (size_t)ng*128 + (m0>>5));
      u16* srow = Sb + (size_t)ng*NSP + m0;
      #pragma unroll
      for (int js=0;js<4;js++){
        bool ok = (mw >> (js*16 + col)) & 1ull;
        float s = ok ? as[js][reg] : -1e30f;
        srow[js*16 + col] = f2b(s);
      }
    }
    __syncthreads();
  }
}

// ---------------- SSA pass B (new): per-row scan + fp64 rescore -> argidx ----------------
__global__ __launch_bounds__(256) void k_ssa_scan(
    const u16* __restrict__ Sb, const float* __restrict__ Qf, const float* __restrict__ Kf,
    int b, int* __restrict__ argidx){
  int wv = threadIdx.x >> 6, lane = threadIdx.x & 63;
  int n = blockIdx.x*4 + wv;
  const u16* srow = Sb + (size_t)n*NSP;
  // lane layout: m = j*1024 + lane*16 + e, j<4, e<16
  v8u sv[8];
  #pragma unroll
  for (int j=0;j<4;j++){
    const v8u* p = (const v8u*)(srow + j*1024 + lane*16);
    sv[j*2]   = p[0];
    sv[j*2+1] = p[1];
  }
  float smax = -3e38f;
  #pragma unroll
  for (int r=0;r<8;r++){
    #pragma unroll
    for (int e=0;e<8;e++) smax = fmaxf(smax, b2f(sv[r][e]));
  }
  smax = fmaxf(smax, __shfl_xor(smax,1));
  smax = fmaxf(smax, __shfl_xor(smax,2));
  smax = fmaxf(smax, __shfl_xor(smax,4));
  smax = fmaxf(smax, __shfl_xor(smax,8));
  smax = fmaxf(smax, __shfl_xor(smax,16));
  smax = fmaxf(smax, __shfl_xor(smax,32));
  int bmg = 0;
  if (smax > -1e29f){
    float thr = smax - 0.10f;
    float4 q4 = *(const float4*)(Qf + ((size_t)(b*NSP + n))*256 + lane*4);
    double bd = -1e308;
    bmg = -1;
    int cand = 0;
    for (int j=0;j<4;j++){
      for (int e=0;e<16;e++){
        float sval = b2f(sv[j*2 + (e>>3)][e&7]);
        u64 bl = __ballot(sval >= thr);
        while (bl && cand < 128){
          int l2 = __builtin_ctzll(bl);
          bl &= bl - 1;
          cand++;
          int mg = j*1024 + l2*16 + e;
          float4 k4 = *(const float4*)(Kf + ((size_t)(b*NSP + mg))*256 + lane*4);
          double d = (double)q4.x*k4.x + (double)q4.y*k4.y + (double)q4.z*k4.z + (double)q4.w*k4.w;
          d += __shfl_xor(d,1); d += __shfl_xor(d,2); d += __shfl_xor(d,4);
          d += __shfl_xor(d,8); d += __shfl_xor(d,16); d += __shfl_xor(d,32);
          if (d > bd || (d == bd && mg < bmg)){ bd = d; bmg = mg; }
        }
      }
    }
    if (bmg < 0) bmg = 0;
  }
  if (lane == 0) argidx[b*NSP + n] = bmg;
}

// ---------------- SSA fallback pass 1: masked row-max of bf16 scores ----------------
__global__ __launch_bounds__(256,2) void k_ssa_max(
    const float* __restrict__ Qf, const u16* __restrict__ Kt,
    const u32* __restrict__ mbits, u32* __restrict__ rowmaxU){
  __shared__ u16 Ks[64][264];
  int mh = blockIdx.x, nt = blockIdx.y, b = blockIdx.z;
  int tid = threadIdx.x, w = tid>>6, lane = tid&63, col = lane&15, q = lane>>4;
  int nw = nt*64 + w*16, mbase = mh*512;
  v8s qf[8];
  const float* qrow = Qf + ((size_t)(b*NSP + nw + col))*256;
  #pragma unroll
  for (int ks=0;ks<8;ks++){
    const float4* qp = (const float4*)(qrow + ks*32 + q*8);
    float4 a = qp[0], c = qp[1];
    v8s f;
    f[0]=(short)f2b(a.x); f[1]=(short)f2b(a.y); f[2]=(short)f2b(a.z); f[3]=(short)f2b(a.w);
    f[4]=(short)f2b(c.x); f[5]=(short)f2b(c.y); f[6]=(short)f2b(c.z); f[7]=(short)f2b(c.w);
    qf[ks] = f;
  }
  float rm[4] = {-1e30f,-1e30f,-1e30f,-1e30f};
  for (int it=0; it<8; it++){
    int m0 = mbase + it*64;
    #pragma unroll
    for (int p=0;p<8;p++){
      int id = tid + p*256;
      int row = id>>5, cc = (id&31)*8;
      *(v8s*)&Ks[row][cc] = *(const v8s*)(Kt + ((size_t)(b*NSP + m0 + row))*256 + cc);
    }
    __syncthreads();
    v4f as[4] = {};
    #pragma unroll
    for (int ks=0;ks<8;ks++){
      #pragma unroll
      for (int js=0;js<4;js++){
        v8s bfr = *(v8s*)&Ks[js*16+col][ks*32+q*8];
        as[js] = __builtin_amdgcn_mfma_f32_16x16x32_bf16(qf[ks], bfr, as[js], 0, 0, 0);
      }
    }
    #pragma unroll
    for (int reg=0;reg<4;reg++){
      int ng = nw + q*4 + reg;
      u64 mw = *(const u64*)(mbits + (size_t)ng*128 + (m0>>5));
      #pragma unroll
      for (int js=0;js<4;js++){
        bool ok = (mw >> (js*16 + col)) & 1ull;
        if (ok) rm[reg] = fmaxf(rm[reg], as[js][reg]);
      }
    }
    __syncthreads();
  }
  #pragma unroll
  for (int reg=0;reg<4;reg++){
    float t = rm[reg];
    t = fmaxf(t, __shfl_xor(t,1));
    t = fmaxf(t, __shfl_xor(t,2));
    t = fmaxf(t, __shfl_xor(t,4));
    t = fmaxf(t, __shfl_xor(t,8));
    if (col == 0){
      int ng = nw + q*4 + reg;
      atomicMax(rowmaxU + (size_t)b*NSP + ng, f2sortable(t));
    }
  }
}

// ---------------- SSA fallback pass 2: candidates, fp64 rescore + atomic argmax ----------------
__global__ __launch_bounds__(256,2) void k_ssa_arg(
    const float* __restrict__ Qf, const u16* __restrict__ Kt,
    const float* __restrict__ Kf, const u32* __restrict__ mbits,
    const u32* __restrict__ rowmaxU, u64* __restrict__ argkey){
  __shared__ u16 Ks[64][264];
  int mh = blockIdx.x, nt = blockIdx.y, b = blockIdx.z;
  int tid = threadIdx.x, w = tid>>6, lane = tid&63, col = lane&15, q = lane>>4;
  int nw = nt*64 + w*16, mbase = mh*512;
  v8s qf[8];
  const float* qrow = Qf + ((size_t)(b*NSP + nw + col))*256;
  #pragma unroll
  for (int ks=0;ks<8;ks++){
    const float4* qp = (const float4*)(qrow + ks*32 + q*8);
    float4 a = qp[0], c = qp[1];
    v8s f;
    f[0]=(short)f2b(a.x); f[1]=(short)f2b(a.y); f[2]=(short)f2b(a.z); f[3]=(short)f2b(a.w);
    f[4]=(short)f2b(c.x); f[5]=(short)f2b(c.y); f[6]=(short)f2b(c.z); f[7]=(short)f2b(c.w);
    qf[ks] = f;
  }
  float thr[4];
  #pragma unroll
  for (int reg=0;reg<4;reg++){
    int ng = nw + q*4 + reg;
    thr[reg] = sortable2f(rowmaxU[(size_t)b*NSP + ng]) - 0.25f;
  }
  for (int it=0; it<8; it++){
    int m0 = mbase + it*64;
    #pragma unroll
    for (int p=0;p<8;p++){
      int id = tid + p*256;
      int row = id>>5, cc = (id&31)*8;
      *(v8s*)&Ks[row][cc] = *(const v8s*)(Kt + ((size_t)(b*NSP + m0 + row))*256 + cc);
    }
    __syncthreads();
    v4f as[4] = {};
    #pragma unroll
    for (int ks=0;ks<8;ks++){
      #pragma unroll
      for (int js=0;js<4;js++){
        v8s bfr = *(v8s*)&Ks[js*16+col][ks*32+q*8];
        as[js] = __builtin_amdgcn_mfma_f32_16x16x32_bf16(qf[ks], bfr, as[js], 0, 0, 0);
      }
    }
    #pragma unroll
    for (int reg=0;reg<4;reg++){
      int ng = nw + q*4 + reg;
      u64 mw = *(const u64*)(mbits + (size_t)ng*128 + (m0>>5));
      #pragma unroll
      for (int js=0;js<4;js++){
        int mg = m0 + js*16 + col;
        bool ok = (mw >> (js*16 + col)) & 1ull;
        if (ok && as[js][reg] >= thr[reg]){
          const float* qr = Qf + ((size_t)(b*NSP + ng))*256;
          const float* kr = Kf + ((size_t)(b*NSP + mg))*256;
          double s0=0.0, s1=0.0;
          for (int c4=0;c4<64;c4++){
            float4 av = *(const float4*)(qr + c4*4);
            float4 bv = *(const float4*)(kr + c4*4);
            s0 += (double)av.x*bv.x + (double)av.z*bv.z;
            s1 += (double)av.y*bv.y + (double)av.w*bv.w;
          }
          double dt = s0 + s1;
          u64 db; __builtin_memcpy(&db, &dt, 8);
          u64 sd = (db & 0x8000000000000000ull) ? ~db : (db | 0x8000000000000000ull);
          u64 key = (sd & ~0xFFFull) | (u64)(4095 - mg);
          atomicMax((unsigned long long*)(argkey + (size_t)b*NSP + ng), (unsigned long long)key);
        }
      }
    }
    __syncthreads();
  }
}

// ---------------- fallback: argkey -> argidx ----------------
__global__ __launch_bounds__(256) void k_key2idx(const u64* __restrict__ argkey, int* __restrict__ argidx){
  int i = blockIdx.x*256 + threadIdx.x;
  if (i < NB*NSP){
    u64 key = argkey[i];
    argidx[i] = 4095 - (int)(key & 0xFFFull);
  }
}

// ---------------- SCA: flash attention (soft), 8-way m-split partials ----------------
__global__ __launch_bounds__(256,2) void k_sca(
    const u16* __restrict__ Qt, const u16* __restrict__ Kt, const u16* __restrict__ Vp,
    const u32* __restrict__ mbits, u16* __restrict__ OpartB, float* __restrict__ lmv){
  __shared__ u16 Ks[32][264];
  __shared__ u16 Vs[256][40];
  __shared__ u16 Ps[4][16][40];
  int mh = blockIdx.x, nt = blockIdx.y, b = blockIdx.z;
  int tid = threadIdx.x, w = tid>>6, lane = tid&63, col = lane&15, q = lane>>4;
  int nw = nt*64 + w*16;
  int mbase = mh*512;
  v8s qf[8];
  const u16* qrow = Qt + ((size_t)(b*NSP + nw + col))*256;
  #pragma unroll
  for (int ks=0;ks<8;ks++) qf[ks] = *(const v8s*)(qrow + ks*32 + q*8);
  v4f ao[16] = {};
  float mr[4]   = {-1e30f,-1e30f,-1e30f,-1e30f};
  float lsum[4] = {0.f,0.f,0.f,0.f};
  for (int it=0; it<16; it++){
    int m0 = mbase + it*32;
    #pragma unroll
    for (int p=0;p<4;p++){
      int id = tid + p*256;
      int row = id>>5, cc = (id&31)*8;
      *(v8s*)&Ks[row][cc] = *(const v8s*)(Kt + ((size_t)(b*NSP + m0 + row))*256 + cc);
    }
    #pragma unroll
    for (int p=0;p<4;p++){
      int id = tid + p*256;
      int row = id>>2, cc = (id&3)*8;
      *(v8s*)&Vs[row][cc] = *(const v8s*)(Vp + ((size_t)(b*CH + row))*NSP + m0 + cc);
    }
    __syncthreads();
    v4f as[2] = {};
    #pragma unroll
    for (int ks=0;ks<8;ks++){
      #pragma unroll
      for (int js=0;js<2;js++){
        v8s bfr = *(v8s*)&Ks[js*16+col][ks*32+q*8];
        as[js] = __builtin_amdgcn_mfma_f32_16x16x32_bf16(qf[ks], bfr, as[js], 0, 0, 0);
      }
    }
    float sv[2][4];
    float tmax[4] = {-1e30f,-1e30f,-1e30f,-1e30f};
    #pragma unroll
    for (int reg=0;reg<4;reg++){
      int ng = nw + q*4 + reg;
      u32 mwrd = mbits[(size_t)ng*128 + (m0>>5)];
      #pragma unroll
      for (int js=0;js<2;js++){
        bool ok = (mwrd >> (js*16 + col)) & 1u;
        float s = ok ? as[js][reg] : -1e30f;
        sv[js][reg] = s;
        tmax[reg] = fmaxf(tmax[reg], s);
      }
    }
    float alpha[4];
    #pragma unroll
    for (int reg=0;reg<4;reg++){
      float t = tmax[reg];
      t = fmaxf(t, __shfl_xor(t,1));
      t = fmaxf(t, __shfl_xor(t,2));
      t = fmaxf(t, __shfl_xor(t,4));
      t = fmaxf(t, __shfl_xor(t,8));
      float mn = fmaxf(mr[reg], t);
      alpha[reg] = __expf(mr[reg] - mn);
      mr[reg] = mn;
    }
    float rs[4] = {0.f,0.f,0.f,0.f};
    #pragma unroll
    for (int js=0;js<2;js++){
      #pragma unroll
      for (int reg=0;reg<4;reg++){
        float s = sv[js][reg];
        float pv = (s <= -1e29f) ? 0.f : __expf(s - mr[reg]);
        Ps[w][q*4+reg][js*16+col] = f2b(pv);
        rs[reg] += pv;
      }
    }
    #pragma unroll
    for (int reg=0;reg<4;reg++){
      float r = rs[reg];
      r += __shfl_xor(r,1); r += __shfl_xor(r,2);
      r += __shfl_xor(r,4); r += __shfl_xor(r,8);
      lsum[reg] = lsum[reg]*alpha[reg] + r;
    }
    v4f al4 = {alpha[0], alpha[1], alpha[2], alpha[3]};
    #pragma unroll
    for (int os=0;os<16;os++) ao[os] *= al4;
    v8s pfr = *(v8s*)&Ps[w][col][q*8];
    #pragma unroll
    for (int os=0;os<16;os++){
      v8s vb = *(v8s*)&Vs[os*16 + col][q*8];
      ao[os] = __builtin_amdgcn_mfma_f32_16x16x32_bf16(pfr, vb, ao[os], 0, 0, 0);
    }
    __syncthreads();
  }
  size_t base = ((size_t)(mh*2 + b))*NSP;
  #pragma unroll
  for (int os=0;os<16;os++){
    #pragma unroll
    for (int reg=0;reg<4;reg++){
      int ng = nw + q*4 + reg;
      OpartB[(base + ng)*256 + os*16 + col] = f2b(ao[os][reg]);
    }
  }
  if (col == 0){
    #pragma unroll
    for (int reg=0;reg<4;reg++){
      int ng = nw + q*4 + reg;
      lmv[(base + ng)*2 + 0] = mr[reg];
      lmv[(base + ng)*2 + 1] = lsum[reg];
    }
  }
}

// ---------------- merge 8 partials + SSA gather + residual -> fp32 out[b][o][n] ----------------
__global__ __launch_bounds__(256) void k_combine(
    const u16* __restrict__ OpartB, const float* __restrict__ lmv,
    const int* __restrict__ argidx, const u16* __restrict__ Vp,
    const float* __restrict__ content, const int* __restrict__ t1p, const int* __restrict__ t2p,
    float* __restrict__ outp){
  __shared__ float T[64][65];
  __shared__ float cs[8][64];
  __shared__ int sidx[64];
  int nt = blockIdx.x, ot = blockIdx.y, b = blockIdx.z;
  int n0 = nt*64, o0 = ot*64, tid = threadIdx.x;
  float t1f = (float)t1p[0], t2f = (float)t2p[0];
  if (tid < 64){
    int ng = n0 + tid;
    sidx[tid] = argidx[b*NSP + ng] & 4095;
    float mp[8], lp[8];
    float M = -1e30f;
    #pragma unroll
    for (int p=0;p<8;p++){
      mp[p] = lmv[(((size_t)(p*2+b))*NSP + ng)*2 + 0];
      lp[p] = lmv[(((size_t)(p*2+b))*NSP + ng)*2 + 1];
      M = fmaxf(M, mp[p]);
    }
    float den = 0.f;
    float wv[8];
    #pragma unroll
    for (int p=0;p<8;p++){ wv[p] = __expf(mp[p] - M); den += lp[p]*wv[p]; }
    float rd = (den > 0.f) ? 1.f/den : 0.f;
    #pragma unroll
    for (int p=0;p<8;p++) cs[p][tid] = wv[p]*rd;
  }
  __syncthreads();
  int jo = tid & 63, bi = tid >> 6;
  #pragma unroll
  for (int p16=0;p16<16;p16++){
    int in_ = bi + p16*4;
    int ng = n0 + in_;
    float acc = 0.f;
    #pragma unroll
    for (int p=0;p<8;p++){
      size_t off = (((size_t)(p*2+b))*NSP + ng)*256 + o0 + jo;
      acc += b2f(OpartB[off])*cs[p][in_];
    }
    T[jo][in_] = acc;
  }
  __syncthreads();
  int nl = tid & 63, ob = tid >> 6;
  #pragma unroll
  for (int p=0;p<16;p++){
    int ol = ob + p*4;
    int og = o0 + ol;
    size_t vrow = ((size_t)(b*CH + og))*NSP;
    float v = t1f*T[ol][nl] + t2f*b2f(Vp[vrow + sidx[nl]]) + content[vrow + n0 + nl];
    outp[vrow + n0 + nl] = v;
  }
}

extern "C" void kernel_launch(void* const* d_in, const int* in_sizes, int n_in,
                              void* d_out, int out_size, void* d_ws, size_t ws_size,
                              hipStream_t stream){
  const float* content = (const float*)d_in[0];
  const float* style   = (const float*)d_in[1];
  const float* csem    = (const float*)d_in[2];
  const float* ssem    = (const float*)d_in[3];
  const float* map64   = (const float*)d_in[5];
  const int* t1p       = (const int*)d_in[6];
  const int* t2p       = (const int*)d_in[7];
  const float* Wf = (const float*)d_in[8];  const float* bfv = (const float*)d_in[9];
  const float* Wg = (const float*)d_in[10]; const float* bgv = (const float*)d_in[11];
  const float* Wh = (const float*)d_in[12]; const float* bhv = (const float*)d_in[13];
  const float* Wo = (const float*)d_in[14]; const float* bov = (const float*)d_in[15];

  char* ws = (char*)d_ws;
  size_t off = 0;
  auto alloc = [&](size_t bytes)->char*{
    char* p = ws + off;
    off += (bytes + 255) & ~(size_t)255;
    return p;
  };
  float* meanv  = (float*)alloc((size_t)4*512*4);
  float* rstdv  = (float*)alloc((size_t)4*512*4);
  float* b2v    = (float*)alloc((size_t)CH*4);
  float* lmv    = (float*)alloc((size_t)8*NB*NSP*2*4);
  u64* argkey   = (u64*)alloc((size_t)NB*NSP*8);
  u32* rowmaxU  = (u32*)alloc((size_t)NB*NSP*4);
  int* argidx   = (int*)alloc((size_t)NB*NSP*4);
  u16* w2       = (u16*)alloc((size_t)CH*CH*2);
  u32* mbits    = (u32*)alloc((size_t)NSP*128*4);
  u16* qt_sca   = (u16*)alloc((size_t)NB*NSP*CH*2);
  u16* kt_sca   = (u16*)alloc((size_t)NB*NSP*CH*2);
  u16* vp       = (u16*)alloc((size_t)NB*CH*NSP*2);
  u16* qt_ssa   = (u16*)alloc((size_t)NB*NSP*CH*2);
  // overlay region: [kt_ssa 4MB | qff 8MB | kff 8MB | tail] reused as opart (33.5MB)
  char* ovl     = alloc((size_t)8*NB*NSP*CH*2);
  u16* kt_ssa   = (u16*)ovl;
  float* qff    = (float*)(ovl + (size_t)NB*NSP*CH*2);
  float* kff    = (float*)(ovl + (size_t)NB*NSP*CH*2 + (size_t)NB*NSP*CH*4);
  u16* opartB   = (u16*)ovl;
  size_t base_need = off;
  u16* Sb       = (u16*)alloc((size_t)NSP*NSP*2);   // 32MB, per-batch score dump
  size_t full_need = off;
  bool bigws = (ws_size >= full_need);
  (void)in_sizes; (void)n_in; (void)out_size; (void)base_need;

  hipMemsetAsync(argkey, 0, (size_t)NB*NSP*8, stream);
  hipMemsetAsync(rowmaxU, 0, (size_t)NB*NSP*4, stream);

  k_stats<<<2048, 256, 0, stream>>>(csem, ssem, content, style, meanv, rstdv);
  k_weights<<<256, 256, 0, stream>>>(Wo, Wh, bhv, bov, w2, b2v);
  k_maskbits<<<2048, 256, 0, stream>>>(map64, mbits);
  k_conv_sca<<<dim3(4,64,2), 256, 0, stream>>>(csem, Wf, meanv, rstdv, 0,    bfv, qt_sca);
  k_conv_sca<<<dim3(4,64,2), 256, 0, stream>>>(ssem, Wg, meanv, rstdv, 512,  bgv, kt_sca);
  k_conv_ssa<<<dim3(4,64,2), 256, 0, stream>>>(content, Wf, meanv, rstdv, 1024, bfv, qff, qt_ssa);
  k_conv_ssa<<<dim3(4,64,2), 256, 0, stream>>>(style,   Wg, meanv, rstdv, 1536, bgv, kff, kt_ssa);
  k_vprime<<<dim3(64,4,2), 256, 0, stream>>>(w2, style, b2v, vp);
  if (bigws){
    // score dump + memory-bound scan/rescore, per batch (Sb reused)
    for (int b=0;b<2;b++){
      k_ssa_dump<<<dim3(8,64,1), 256, 0, stream>>>(qt_ssa, kt_ssa, mbits, b, Sb);
      k_ssa_scan<<<1024, 256, 0, stream>>>(Sb, qff, kff, b, argidx);
    }
  } else {
    k_ssa_max<<<dim3(8,64,2), 256, 0, stream>>>(qff, kt_ssa, mbits, rowmaxU);
    k_ssa_arg<<<dim3(8,64,2), 256, 0, stream>>>(qff, kt_ssa, kff, mbits, rowmaxU, argkey);
    k_key2idx<<<32, 256, 0, stream>>>(argkey, argidx);
  }
  k_sca<<<dim3(8,64,2), 256, 0, stream>>>(qt_sca, kt_sca, vp, mbits, opartB, lmv);
  k_combine<<<dim3(64,4,2), 256, 0, stream>>>(opartB, lmv, argidx, vp, content, t1p, t2p, (float*)d_out);
}

// Round 7
// 493.055 us; speedup vs baseline: 2.9661x; 2.9661x over previous
//
#include <hip/hip_runtime.h>
#include <hip/hip_bf16.h>
#include <cstddef>

typedef unsigned short u16;
typedef unsigned int   u32;
typedef unsigned long long u64;
typedef short v8s __attribute__((ext_vector_type(8)));
typedef u16   v8u __attribute__((ext_vector_type(8)));
typedef float v4f __attribute__((ext_vector_type(4)));

#define CH  256
#define NSP 4096
#define NB  2

__device__ __forceinline__ float b2f(u16 u){ u32 t = ((u32)u) << 16; float f; __builtin_memcpy(&f, &t, 4); return f; }
__device__ __forceinline__ u16 f2b(float f){
  u32 x; __builtin_memcpy(&x, &f, 4);
  u32 r = x + 0x7FFFu + ((x >> 16) & 1u);
  return (u16)(r >> 16);
}

// ---------------- per-(b,c) mean / rstd over fp32 input (fp64 accumulate) ----------------
__global__ __launch_bounds__(256) void k_stats(
    const float* __restrict__ x0, const float* __restrict__ x1,
    const float* __restrict__ x2, const float* __restrict__ x3,
    float* __restrict__ meanv, float* __restrict__ rstdv){
  int bid = blockIdx.x;            // t*512 + row
  int t = bid >> 9, row = bid & 511;
  const float* src = (t==0?x0: t==1?x1: t==2?x2: x3) + (size_t)row*NSP;
  int tid = threadIdx.x;
  double sx = 0.0, sq = 0.0;
  const float4* p4 = (const float4*)src;
  #pragma unroll
  for (int k=0;k<4;k++){
    float4 v = p4[tid + k*256];
    double a=v.x,bb=v.y,c=v.z,d=v.w;
    sx += a+bb+c+d;
    sq += a*a + bb*bb + c*c + d*d;
  }
  #pragma unroll
  for (int off=1; off<64; off<<=1){ sx += __shfl_xor(sx, off); sq += __shfl_xor(sq, off); }
  __shared__ double wsx[4], wsq[4];
  int w = tid >> 6;
  if ((tid & 63) == 0){ wsx[w] = sx; wsq[w] = sq; }
  __syncthreads();
  if (tid == 0){
    double SX = wsx[0]+wsx[1]+wsx[2]+wsx[3];
    double SQ = wsq[0]+wsq[1]+wsq[2]+wsq[3];
    double mean = SX / 4096.0;
    double var  = (SQ - 4096.0*mean*mean) / 4095.0;
    double rstd = 1.0 / sqrt(var + 1e-5);
    meanv[bid] = (float)mean;
    rstdv[bid] = (float)rstd;
  }
}

// ---------------- weight prep: W2 = Wo@Wh (bf16 out), b2 = Wo@bh + bo ----------------
__global__ __launch_bounds__(256) void k_weights(
    const float* __restrict__ Wo, const float* __restrict__ Wh,
    const float* __restrict__ bh, const float* __restrict__ bo,
    u16* __restrict__ W2, float* __restrict__ b2v){
  int o = blockIdx.x, c = threadIdx.x;
  __shared__ float wo[256];
  __shared__ float red[256];
  wo[c] = Wo[o*256 + c];
  __syncthreads();
  float acc = 0.f;
  for (int j=0;j<256;j++) acc += wo[j] * Wh[j*256 + c];
  W2[o*256 + c] = f2b(acc);
  red[c] = wo[c] * bh[c];
  __syncthreads();
  for (int s=128;s>0;s>>=1){ if (c < s) red[c] += red[c+s]; __syncthreads(); }
  if (c == 0) b2v[o] = red[0] + bo[o];
}

// ---------------- mask bitmap: bit=1 where map >= 0.5 (keep) ----------------
__global__ __launch_bounds__(256) void k_maskbits(
    const float* __restrict__ map, u32* __restrict__ bits){
  int wid = blockIdx.x*256 + threadIdx.x;      // [0, 4096*128)
  const float4* p = (const float4*)(map + (size_t)wid*32);
  u32 m = 0;
  #pragma unroll
  for (int k=0;k<8;k++){
    float4 v = p[k];
    m |= (u32)(v.x >= 0.5f) << (k*4+0);
    m |= (u32)(v.y >= 0.5f) << (k*4+1);
    m |= (u32)(v.z >= 0.5f) << (k*4+2);
    m |= (u32)(v.w >= 0.5f) << (k*4+3);
  }
  bits[wid] = m;
}

// ---------- SCA conv (approx): out[b][n][o]=bf16( sum_c W[o][c]*mvn(x)[c][n] + bias[o] ) ----------
__global__ __launch_bounds__(256,2) void k_conv_sca(
    const float* __restrict__ x, const float* __restrict__ W,
    const float* __restrict__ meanv, const float* __restrict__ rstdv, int statBase,
    const float* __restrict__ biasv, u16* __restrict__ outB){
  __shared__ u16 As[64][72];
  __shared__ u16 Bs[64][72];
  int o0 = blockIdx.x*64, n0 = blockIdx.y*64, b = blockIdx.z;
  int tid = threadIdx.x, w = tid>>6, lane = tid&63, col = lane&15, q = lane>>4;
  v4f acc[4] = {};
  int crA = tid>>2, nseg = (tid&3)*16;
  for (int kc=0; kc<4; kc++){
    int cg = kc*64;
    { // A: mvn + bf16 + transpose
      int srow = statBase + b*256 + cg + crA;
      float mean = meanv[srow], rstd = rstdv[srow];
      const float4* xr = (const float4*)(x + ((size_t)(b*256 + cg + crA))*NSP + n0 + nseg);
      #pragma unroll
      for (int k4=0;k4<4;k4++){
        float4 v = xr[k4];
        As[nseg+k4*4+0][crA] = f2b((v.x-mean)*rstd);
        As[nseg+k4*4+1][crA] = f2b((v.y-mean)*rstd);
        As[nseg+k4*4+2][crA] = f2b((v.z-mean)*rstd);
        As[nseg+k4*4+3][crA] = f2b((v.w-mean)*rstd);
      }
    }
    { // B: weights rows
      const float4* wr = (const float4*)(W + ((size_t)(o0 + crA))*256 + cg + nseg);
      #pragma unroll
      for (int h=0;h<2;h++){
        float4 a = wr[h*2], c = wr[h*2+1];
        v8u o;
        o[0]=f2b(a.x); o[1]=f2b(a.y); o[2]=f2b(a.z); o[3]=f2b(a.w);
        o[4]=f2b(c.x); o[5]=f2b(c.y); o[6]=f2b(c.z); o[7]=f2b(c.w);
        *(v8u*)&Bs[crA][nseg + h*8] = o;
      }
    }
    __syncthreads();
    #pragma unroll
    for (int ks=0;ks<2;ks++){
      v8s af = *(v8s*)&As[w*16 + col][ks*32 + q*8];
      #pragma unroll
      for (int js=0;js<4;js++){
        v8s bfr = *(v8s*)&Bs[js*16 + col][ks*32 + q*8];
        acc[js] = __builtin_amdgcn_mfma_f32_16x16x32_bf16(af, bfr, acc[js], 0, 0, 0);
      }
    }
    __syncthreads();
  }
  #pragma unroll
  for (int js=0;js<4;js++){
    int o = o0 + js*16 + col;
    float bj = biasv[o];
    #pragma unroll
    for (int reg=0;reg<4;reg++){
      int n = n0 + w*16 + q*4 + reg;
      outB[((size_t)(b*NSP + n))*256 + o] = f2b(acc[js][reg] + bj);
    }
  }
}

// ---------- SSA conv (fp32-exact): 6-term bf16 split (i+j<=2), fp32 out (+opt bf16) ----------
__global__ __launch_bounds__(256,2) void k_conv_ssa(
    const float* __restrict__ x, const float* __restrict__ W,
    const float* __restrict__ meanv, const float* __restrict__ rstdv, int statBase,
    const float* __restrict__ biasv,
    float* __restrict__ outF, u16* __restrict__ outB){
  __shared__ u32 As32[64][100];
  __shared__ u32 Bs32[64][100];
  int o0 = blockIdx.x*64, n0 = blockIdx.y*64, b = blockIdx.z;
  int tid = threadIdx.x, w = tid>>6, lane = tid&63, col = lane&15, q = lane>>4;
  v4f acc[4] = {};
  int cA = tid>>3, nnA = (tid&7)*8;
  int oB = tid>>2, cB = (tid&3)*8;
  for (int g=0; g<8; g++){
    int cg = g*32;
    { // A: mvn + 3-way split, slots per ch: (x0,x1,x2,x0,x1,x0)
      int srow = statBase + b*256 + cg + cA;
      float mean = meanv[srow], rstd = rstdv[srow];
      const float4* xr = (const float4*)(x + ((size_t)(b*256 + cg + cA))*NSP + n0 + nnA);
      float4 v0 = xr[0], v1 = xr[1];
      float xv[8] = {v0.x,v0.y,v0.z,v0.w,v1.x,v1.y,v1.z,v1.w};
      #pragma unroll
      for (int e=0;e<8;e++){
        float xm = (xv[e]-mean)*rstd;
        u16 s0 = f2b(xm);  float r1 = xm - b2f(s0);
        u16 s1 = f2b(r1);  float r2 = r1 - b2f(s1);
        u16 s2 = f2b(r2);
        As32[nnA+e][cA*3+0] = (u32)s0 | ((u32)s1<<16);
        As32[nnA+e][cA*3+1] = (u32)s2 | ((u32)s0<<16);
        As32[nnA+e][cA*3+2] = (u32)s1 | ((u32)s0<<16);
      }
    }
    { // B: 3-way split of W, slots per ch: (w0,w0,w0,w1,w1,w2)
      const float4* wr = (const float4*)(W + ((size_t)(o0 + oB))*256 + cg + cB);
      float4 w0v = wr[0], w1v = wr[1];
      float wv[8] = {w0v.x,w0v.y,w0v.z,w0v.w,w1v.x,w1v.y,w1v.z,w1v.w};
      #pragma unroll
      for (int e=0;e<8;e++){
        float ww = wv[e];
        u16 t0 = f2b(ww);  float r1 = ww - b2f(t0);
        u16 t1 = f2b(r1);  float r2 = r1 - b2f(t1);
        u16 t2 = f2b(r2);
        int cc = cB + e;
        Bs32[oB][cc*3+0] = (u32)t0 | ((u32)t0<<16);
        Bs32[oB][cc*3+1] = (u32)t0 | ((u32)t1<<16);
        Bs32[oB][cc*3+2] = (u32)t1 | ((u32)t2<<16);
      }
    }
    __syncthreads();
    #pragma unroll
    for (int ks=0;ks<6;ks++){
      v8s af = *(v8s*)&As32[w*16 + col][ks*16 + q*4];
      #pragma unroll
      for (int js=0;js<4;js++){
        v8s bfr = *(v8s*)&Bs32[js*16 + col][ks*16 + q*4];
        acc[js] = __builtin_amdgcn_mfma_f32_16x16x32_bf16(af, bfr, acc[js], 0, 0, 0);
      }
    }
    __syncthreads();
  }
  #pragma unroll
  for (int js=0;js<4;js++){
    int o = o0 + js*16 + col;
    float bj = biasv[o];
    #pragma unroll
    for (int reg=0;reg<4;reg++){
      int n = n0 + w*16 + q*4 + reg;
      float v = acc[js][reg] + bj;
      size_t idx = ((size_t)(b*NSP + n))*256 + o;
      outF[idx] = v;
      if (outB) outB[idx] = f2b(v);
    }
  }
}

// ---------------- V' = W2 @ style + b2 -> vp[b][o][m] (bf16) ----------------
__global__ __launch_bounds__(256,2) void k_vprime(
    const u16* __restrict__ w2, const float* __restrict__ style,
    const float* __restrict__ b2v, u16* __restrict__ vp){
  __shared__ u16 As[64][72];
  __shared__ u16 Bs[64][72];
  int m0 = blockIdx.x*64, o0 = blockIdx.y*64, b = blockIdx.z;
  int tid = threadIdx.x, w = tid>>6, lane = tid&63, col = lane&15, q = lane>>4;
  v4f acc[4] = {};
  for (int kc=0; kc<4; kc++){
    int cg = kc*64;
    #pragma unroll
    for (int p=0;p<2;p++){
      int id = tid + p*256;
      int row = id>>3, cc = (id&7)*8;
      *(v8s*)&As[row][cc] = *(const v8s*)(w2 + ((size_t)(o0+row))*256 + cg + cc);
    }
    {
      int cr = tid>>2, mseg = (tid&3)*16;
      const float4* sr = (const float4*)(style + ((size_t)(b*256 + cg + cr))*NSP + m0 + mseg);
      #pragma unroll
      for (int k4=0;k4<4;k4++){
        float4 v = sr[k4];
        Bs[mseg+k4*4+0][cr] = f2b(v.x);
        Bs[mseg+k4*4+1][cr] = f2b(v.y);
        Bs[mseg+k4*4+2][cr] = f2b(v.z);
        Bs[mseg+k4*4+3][cr] = f2b(v.w);
      }
    }
    __syncthreads();
    #pragma unroll
    for (int ks=0;ks<2;ks++){
      v8s af = *(v8s*)&As[w*16+col][ks*32+q*8];
      #pragma unroll
      for (int js=0;js<4;js++){
        v8s bfr = *(v8s*)&Bs[js*16+col][ks*32+q*8];
        acc[js] = __builtin_amdgcn_mfma_f32_16x16x32_bf16(af, bfr, acc[js], 0,0,0);
      }
    }
    __syncthreads();
  }
  #pragma unroll
  for (int js=0;js<4;js++){
    int m = m0 + js*16 + col;
    #pragma unroll
    for (int reg=0;reg<4;reg++){
      int o = o0 + w*16 + q*4 + reg;
      vp[((size_t)(b*CH + o))*NSP + m] = f2b(acc[js][reg] + b2v[o]);
    }
  }
}

// ------- SSA pass A: masked bf16 score dump + PER-SLICE top-2 partials (no races) -------
__global__ __launch_bounds__(256,2) void k_ssa_dump3(
    const u16* __restrict__ Qt, const u16* __restrict__ Kt,
    const u32* __restrict__ mbits, int b, u16* __restrict__ Sb,
    float2* __restrict__ pt, int* __restrict__ pi){
  __shared__ u16 Ks[64][264];
  int mh = blockIdx.x, nt = blockIdx.y;
  int tid = threadIdx.x, w = tid>>6, lane = tid&63, col = lane&15, q = lane>>4;
  int nw = nt*64 + w*16, mbase = mh*512;
  v8s qf[8];
  const u16* qrow = Qt + ((size_t)(b*NSP + nw + col))*256;
  #pragma unroll
  for (int ks=0;ks<8;ks++) qf[ks] = *(const v8s*)(qrow + ks*32 + q*8);
  float t1[4] = {-1e30f,-1e30f,-1e30f,-1e30f};
  float t2[4] = {-1e30f,-1e30f,-1e30f,-1e30f};
  int   i1[4] = {0,0,0,0};
  for (int it=0; it<8; it++){
    int m0 = mbase + it*64;
    #pragma unroll
    for (int p=0;p<8;p++){
      int id = tid + p*256;
      int row = id>>5, cc = (id&31)*8;
      *(v8s*)&Ks[row][cc] = *(const v8s*)(Kt + ((size_t)(b*NSP + m0 + row))*256 + cc);
    }
    __syncthreads();
    v4f as[4] = {};
    #pragma unroll
    for (int ks=0;ks<8;ks++){
      #pragma unroll
      for (int js=0;js<4;js++){
        v8s bfr = *(v8s*)&Ks[js*16+col][ks*32+q*8];
        as[js] = __builtin_amdgcn_mfma_f32_16x16x32_bf16(qf[ks], bfr, as[js], 0, 0, 0);
      }
    }
    #pragma unroll
    for (int reg=0;reg<4;reg++){
      int ng = nw + q*4 + reg;
      u64 mw = *(const u64*)(mbits + (size_t)ng*128 + (m0>>5));
      u16* srow = Sb + (size_t)ng*NSP + m0;
      #pragma unroll
      for (int js=0;js<4;js++){
        int mg = m0 + js*16 + col;
        bool ok = (mw >> (js*16 + col)) & 1ull;
        float s = ok ? as[js][reg] : -1e30f;
        u16 sh = f2b(s);
        float sb = b2f(sh);
        srow[js*16 + col] = sh;
        if (sb > t1[reg]){ t2[reg] = t1[reg]; t1[reg] = sb; i1[reg] = mg; }
        else {
          if (sb == t1[reg] && mg < i1[reg]) i1[reg] = mg;
          t2[reg] = fmaxf(t2[reg], sb);
        }
      }
    }
    __syncthreads();
  }
  // merge top-2 across the 16 col lanes (butterfly within the q-group)
  #pragma unroll
  for (int reg=0;reg<4;reg++){
    #pragma unroll
    for (int off=1; off<16; off<<=1){
      float o1 = __shfl_xor(t1[reg], off);
      int   oi = __shfl_xor(i1[reg], off);
      float o2 = __shfl_xor(t2[reg], off);
      if (o1 > t1[reg]){ t2[reg] = fmaxf(t1[reg], o2); t1[reg] = o1; i1[reg] = oi; }
      else if (o1 == t1[reg]){ i1[reg] = min(i1[reg], oi); t2[reg] = t1[reg]; }
      else { t2[reg] = fmaxf(t2[reg], o1); }
    }
    if (col == 0){
      int ng = nw + q*4 + reg;
      pt[(size_t)mh*NSP + ng] = make_float2(t1[reg], t2[reg]);
      pi[mh*NSP + ng] = i1[reg];
    }
  }
}

// ------- SSA pass A2: merge 8 per-slice partials -> rowmax + decisive argidx / worklist -------
__global__ __launch_bounds__(256) void k_ssa_merge(
    const float2* __restrict__ pt, const int* __restrict__ pi,
    int b, float* __restrict__ rowmaxF, int* __restrict__ argidx,
    int* __restrict__ wl, int* __restrict__ wlc){
  int ng = blockIdx.x*256 + threadIdx.x;   // 16 blocks x 256 = 4096 rows
  float t1 = -3e38f, t2 = -3e38f; int i1 = 0;
  #pragma unroll
  for (int p=0;p<8;p++){
    float2 o = pt[(size_t)p*NSP + ng];
    int oi = pi[p*NSP + ng];
    if (o.x > t1){ t2 = fmaxf(t1, o.y); t1 = o.x; i1 = oi; }
    else if (o.x == t1){ i1 = min(i1, oi); t2 = t1; }
    else { t2 = fmaxf(t2, o.x); }
  }
  rowmaxF[b*NSP + ng] = t1;
  if (t1 - t2 > 0.10f){
    argidx[b*NSP + ng] = i1;
  } else {
    int slot = atomicAdd(wlc, 1);
    wl[slot] = ng;
  }
}

// ------- SSA pass B: resolve ambiguous rows only (static-indexed scan + fp64 rescore) -------
__global__ __launch_bounds__(256) void k_ssa_resolve(
    const u16* __restrict__ Sb, const float* __restrict__ Qf, const float* __restrict__ Kf,
    const float* __restrict__ rowmaxF, const int* __restrict__ wl, const int* __restrict__ wlc,
    int b, int* __restrict__ argidx){
  int wv = threadIdx.x >> 6, lane = threadIdx.x & 63;
  int cnt = wlc[0];
  int slot = blockIdx.x*4 + wv;
  if (slot >= cnt) return;
  int n = wl[slot];
  float rmx = rowmaxF[b*NSP + n];
  int bmg = 0;
  if (rmx > -1e29f){
    const u16* srow = Sb + (size_t)n*NSP;
    v8u sv[8];
    #pragma unroll
    for (int j=0;j<4;j++){
      const v8u* p = (const v8u*)(srow + j*1024 + lane*16);
      sv[j*2]   = p[0];
      sv[j*2+1] = p[1];
    }
    float thr = rmx - 0.10f;
    float4 q4 = *(const float4*)(Qf + ((size_t)(b*NSP + n))*256 + lane*4);
    double bd = -1e308;
    bmg = -1;
    int cand = 0;
    #pragma unroll
    for (int j=0;j<4;j++){
      #pragma unroll
      for (int e=0;e<16;e++){
        float sval = b2f(sv[j*2 + (e>>3)][e&7]);
        u64 bl = __ballot(sval >= thr);
        while (bl && cand < 128){
          int l2 = __builtin_ctzll(bl);
          bl &= bl - 1;
          cand++;
          int mg = j*1024 + l2*16 + e;
          float4 k4 = *(const float4*)(Kf + ((size_t)(b*NSP + mg))*256 + lane*4);
          double d = (double)q4.x*k4.x + (double)q4.y*k4.y + (double)q4.z*k4.z + (double)q4.w*k4.w;
          d += __shfl_xor(d,1); d += __shfl_xor(d,2); d += __shfl_xor(d,4);
          d += __shfl_xor(d,8); d += __shfl_xor(d,16); d += __shfl_xor(d,32);
          if (d > bd || (d == bd && mg < bmg)){ bd = d; bmg = mg; }
        }
      }
    }
    if (bmg < 0) bmg = 0;
  }
  if (lane == 0) argidx[b*NSP + n] = bmg;
}

// ---------------- SCA: flash attention (soft), 8-way m-split partials ----------------
__global__ __launch_bounds__(256,2) void k_sca(
    const u16* __restrict__ Qt, const u16* __restrict__ Kt, const u16* __restrict__ Vp,
    const u32* __restrict__ mbits, u16* __restrict__ OpartB, float* __restrict__ lmv){
  __shared__ u16 Ks[32][264];
  __shared__ u16 Vs[256][40];
  __shared__ u16 Ps[4][16][40];
  int mh = blockIdx.x, nt = blockIdx.y, b = blockIdx.z;
  int tid = threadIdx.x, w = tid>>6, lane = tid&63, col = lane&15, q = lane>>4;
  int nw = nt*64 + w*16;
  int mbase = mh*512;
  v8s qf[8];
  const u16* qrow = Qt + ((size_t)(b*NSP + nw + col))*256;
  #pragma unroll
  for (int ks=0;ks<8;ks++) qf[ks] = *(const v8s*)(qrow + ks*32 + q*8);
  v4f ao[16] = {};
  float mr[4]   = {-1e30f,-1e30f,-1e30f,-1e30f};
  float lsum[4] = {0.f,0.f,0.f,0.f};
  for (int it=0; it<16; it++){
    int m0 = mbase + it*32;
    #pragma unroll
    for (int p=0;p<4;p++){
      int id = tid + p*256;
      int row = id>>5, cc = (id&31)*8;
      *(v8s*)&Ks[row][cc] = *(const v8s*)(Kt + ((size_t)(b*NSP + m0 + row))*256 + cc);
    }
    #pragma unroll
    for (int p=0;p<4;p++){
      int id = tid + p*256;
      int row = id>>2, cc = (id&3)*8;
      *(v8s*)&Vs[row][cc] = *(const v8s*)(Vp + ((size_t)(b*CH + row))*NSP + m0 + cc);
    }
    __syncthreads();
    v4f as[2] = {};
    #pragma unroll
    for (int ks=0;ks<8;ks++){
      #pragma unroll
      for (int js=0;js<2;js++){
        v8s bfr = *(v8s*)&Ks[js*16+col][ks*32+q*8];
        as[js] = __builtin_amdgcn_mfma_f32_16x16x32_bf16(qf[ks], bfr, as[js], 0, 0, 0);
      }
    }
    float sv[2][4];
    float tmax[4] = {-1e30f,-1e30f,-1e30f,-1e30f};
    #pragma unroll
    for (int reg=0;reg<4;reg++){
      int ng = nw + q*4 + reg;
      u32 mwrd = mbits[(size_t)ng*128 + (m0>>5)];
      #pragma unroll
      for (int js=0;js<2;js++){
        bool ok = (mwrd >> (js*16 + col)) & 1u;
        float s = ok ? as[js][reg] : -1e30f;
        sv[js][reg] = s;
        tmax[reg] = fmaxf(tmax[reg], s);
      }
    }
    float alpha[4];
    #pragma unroll
    for (int reg=0;reg<4;reg++){
      float t = tmax[reg];
      t = fmaxf(t, __shfl_xor(t,1));
      t = fmaxf(t, __shfl_xor(t,2));
      t = fmaxf(t, __shfl_xor(t,4));
      t = fmaxf(t, __shfl_xor(t,8));
      float mn = fmaxf(mr[reg], t);
      alpha[reg] = __expf(mr[reg] - mn);
      mr[reg] = mn;
    }
    float rs[4] = {0.f,0.f,0.f,0.f};
    #pragma unroll
    for (int js=0;js<2;js++){
      #pragma unroll
      for (int reg=0;reg<4;reg++){
        float s = sv[js][reg];
        float pv = (s <= -1e29f) ? 0.f : __expf(s - mr[reg]);
        Ps[w][q*4+reg][js*16+col] = f2b(pv);
        rs[reg] += pv;
      }
    }
    #pragma unroll
    for (int reg=0;reg<4;reg++){
      float r = rs[reg];
      r += __shfl_xor(r,1); r += __shfl_xor(r,2);
      r += __shfl_xor(r,4); r += __shfl_xor(r,8);
      lsum[reg] = lsum[reg]*alpha[reg] + r;
    }
    v4f al4 = {alpha[0], alpha[1], alpha[2], alpha[3]};
    #pragma unroll
    for (int os=0;os<16;os++) ao[os] *= al4;
    v8s pfr = *(v8s*)&Ps[w][col][q*8];
    #pragma unroll
    for (int os=0;os<16;os++){
      v8s vb = *(v8s*)&Vs[os*16 + col][q*8];
      ao[os] = __builtin_amdgcn_mfma_f32_16x16x32_bf16(pfr, vb, ao[os], 0, 0, 0);
    }
    __syncthreads();
  }
  size_t base = ((size_t)(mh*2 + b))*NSP;
  #pragma unroll
  for (int os=0;os<16;os++){
    #pragma unroll
    for (int reg=0;reg<4;reg++){
      int ng = nw + q*4 + reg;
      OpartB[(base + ng)*256 + os*16 + col] = f2b(ao[os][reg]);
    }
  }
  if (col == 0){
    #pragma unroll
    for (int reg=0;reg<4;reg++){
      int ng = nw + q*4 + reg;
      lmv[(base + ng)*2 + 0] = mr[reg];
      lmv[(base + ng)*2 + 1] = lsum[reg];
    }
  }
}

// ---------------- merge 8 partials + SSA gather + residual -> fp32 out[b][o][n] ----------------
__global__ __launch_bounds__(256) void k_combine(
    const u16* __restrict__ OpartB, const float* __restrict__ lmv,
    const int* __restrict__ argidx, const u16* __restrict__ Vp,
    const float* __restrict__ content, const int* __restrict__ t1p, const int* __restrict__ t2p,
    float* __restrict__ outp){
  __shared__ float T[64][65];
  __shared__ float cs[8][64];
  __shared__ int sidx[64];
  int nt = blockIdx.x, ot = blockIdx.y, b = blockIdx.z;
  int n0 = nt*64, o0 = ot*64, tid = threadIdx.x;
  float t1f = (float)t1p[0], t2f = (float)t2p[0];
  if (tid < 64){
    int ng = n0 + tid;
    sidx[tid] = argidx[b*NSP + ng] & 4095;
    float mp[8], lp[8];
    float M = -1e30f;
    #pragma unroll
    for (int p=0;p<8;p++){
      mp[p] = lmv[(((size_t)(p*2+b))*NSP + ng)*2 + 0];
      lp[p] = lmv[(((size_t)(p*2+b))*NSP + ng)*2 + 1];
      M = fmaxf(M, mp[p]);
    }
    float den = 0.f;
    float wv[8];
    #pragma unroll
    for (int p=0;p<8;p++){ wv[p] = __expf(mp[p] - M); den += lp[p]*wv[p]; }
    float rd = (den > 0.f) ? 1.f/den : 0.f;
    #pragma unroll
    for (int p=0;p<8;p++) cs[p][tid] = wv[p]*rd;
  }
  __syncthreads();
  int jo = tid & 63, bi = tid >> 6;
  #pragma unroll
  for (int p16=0;p16<16;p16++){
    int in_ = bi + p16*4;
    int ng = n0 + in_;
    float acc = 0.f;
    #pragma unroll
    for (int p=0;p<8;p++){
      size_t off = (((size_t)(p*2+b))*NSP + ng)*256 + o0 + jo;
      acc += b2f(OpartB[off])*cs[p][in_];
    }
    T[jo][in_] = acc;
  }
  __syncthreads();
  int nl = tid & 63, ob = tid >> 6;
  #pragma unroll
  for (int p=0;p<16;p++){
    int ol = ob + p*4;
    int og = o0 + ol;
    size_t vrow = ((size_t)(b*CH + og))*NSP;
    float v = t1f*T[ol][nl] + t2f*b2f(Vp[vrow + sidx[nl]]) + content[vrow + n0 + nl];
    outp[vrow + n0 + nl] = v;
  }
}

extern "C" void kernel_launch(void* const* d_in, const int* in_sizes, int n_in,
                              void* d_out, int out_size, void* d_ws, size_t ws_size,
                              hipStream_t stream){
  const float* content = (const float*)d_in[0];
  const float* style   = (const float*)d_in[1];
  const float* csem    = (const float*)d_in[2];
  const float* ssem    = (const float*)d_in[3];
  const float* map64   = (const float*)d_in[5];
  const int* t1p       = (const int*)d_in[6];
  const int* t2p       = (const int*)d_in[7];
  const float* Wf = (const float*)d_in[8];  const float* bfv = (const float*)d_in[9];
  const float* Wg = (const float*)d_in[10]; const float* bgv = (const float*)d_in[11];
  const float* Wh = (const float*)d_in[12]; const float* bhv = (const float*)d_in[13];
  const float* Wo = (const float*)d_in[14]; const float* bov = (const float*)d_in[15];

  char* ws = (char*)d_ws;
  size_t off = 0;
  auto alloc = [&](size_t bytes)->char*{
    char* p = ws + off;
    off += (bytes + 255) & ~(size_t)255;
    return p;
  };
  float* meanv  = (float*)alloc((size_t)4*512*4);
  float* rstdv  = (float*)alloc((size_t)4*512*4);
  float* b2v    = (float*)alloc((size_t)CH*4);
  float* lmv    = (float*)alloc((size_t)8*NB*NSP*2*4);
  float* rowmaxF= (float*)alloc((size_t)NB*NSP*4);
  int* argidx   = (int*)alloc((size_t)NB*NSP*4);
  int* wl       = (int*)alloc((size_t)NB*NSP*4);
  int* wlc      = (int*)alloc((size_t)NB*4);
  float2* pt    = (float2*)alloc((size_t)8*NSP*8);
  int* pi       = (int*)alloc((size_t)8*NSP*4);
  u16* w2       = (u16*)alloc((size_t)CH*CH*2);
  u32* mbits    = (u32*)alloc((size_t)NSP*128*4);
  u16* qt_sca   = (u16*)alloc((size_t)NB*NSP*CH*2);
  u16* kt_sca   = (u16*)alloc((size_t)NB*NSP*CH*2);
  u16* vp       = (u16*)alloc((size_t)NB*CH*NSP*2);
  u16* qt_ssa   = (u16*)alloc((size_t)NB*NSP*CH*2);
  // overlay region: [kt_ssa 4MB | qff 8MB | kff 8MB | tail] reused as opart (33.5MB)
  char* ovl     = alloc((size_t)8*NB*NSP*CH*2);
  u16* kt_ssa   = (u16*)ovl;
  float* qff    = (float*)(ovl + (size_t)NB*NSP*CH*2);
  float* kff    = (float*)(ovl + (size_t)NB*NSP*CH*2 + (size_t)NB*NSP*CH*4);
  u16* opartB   = (u16*)ovl;
  u16* Sb       = (u16*)alloc((size_t)NSP*NSP*2);   // 32MB, per-batch score dump
  (void)in_sizes; (void)n_in; (void)out_size; (void)ws_size;

  hipMemsetAsync(wlc, 0, (size_t)NB*4, stream);

  k_stats<<<2048, 256, 0, stream>>>(csem, ssem, content, style, meanv, rstdv);
  k_weights<<<256, 256, 0, stream>>>(Wo, Wh, bhv, bov, w2, b2v);
  k_maskbits<<<2048, 256, 0, stream>>>(map64, mbits);
  k_conv_sca<<<dim3(4,64,2), 256, 0, stream>>>(csem, Wf, meanv, rstdv, 0,    bfv, qt_sca);
  k_conv_sca<<<dim3(4,64,2), 256, 0, stream>>>(ssem, Wg, meanv, rstdv, 512,  bgv, kt_sca);
  k_conv_ssa<<<dim3(4,64,2), 256, 0, stream>>>(content, Wf, meanv, rstdv, 1024, bfv, qff, qt_ssa);
  k_conv_ssa<<<dim3(4,64,2), 256, 0, stream>>>(style,   Wg, meanv, rstdv, 1536, bgv, kff, kt_ssa);
  k_vprime<<<dim3(64,4,2), 256, 0, stream>>>(w2, style, b2v, vp);
  for (int b=0;b<2;b++){
    k_ssa_dump3<<<dim3(8,64,1), 256, 0, stream>>>(qt_ssa, kt_ssa, mbits, b, Sb, pt, pi);
    k_ssa_merge<<<16, 256, 0, stream>>>(pt, pi, b, rowmaxF, argidx, wl + b*NSP, wlc + b);
    k_ssa_resolve<<<1024, 256, 0, stream>>>(Sb, qff, kff, rowmaxF, wl + b*NSP, wlc + b, b, argidx);
  }
  k_sca<<<dim3(8,64,2), 256, 0, stream>>>(qt_sca, kt_sca, vp, mbits, opartB, lmv);
  k_combine<<<dim3(64,4,2), 256, 0, stream>>>(opartB, lmv, argidx, vp, content, t1p, t2p, (float*)d_out);
}